// Round 2
// baseline (304.490 us; speedup 1.0000x reference)
//
#include <hip/hip_runtime.h>
#include <hip/hip_bf16.h>

typedef unsigned short u16;
typedef short bf16x8 __attribute__((ext_vector_type(8)));
typedef float f32x4 __attribute__((ext_vector_type(4)));
typedef u16 us8 __attribute__((ext_vector_type(8)));

#define NEGV -10000.0f

static __device__ __forceinline__ u16 f2bf(float f) {
    __hip_bfloat16 h = __float2bfloat16(f);
    return __builtin_bit_cast(u16, h);
}

#define GLOAD_LDS16(g, l)                                                      \
    __builtin_amdgcn_global_load_lds(                                          \
        (const __attribute__((address_space(1))) void*)(g),                    \
        (__attribute__((address_space(3))) void*)(l), 16, 0, 0)

// ---------------- fp32 -> bf16 convert ----------------
__global__ __launch_bounds__(256) void cvt_bf16(const float* __restrict__ src,
                                                u16* __restrict__ dst, int n4) {
    int i = blockIdx.x * 256 + threadIdx.x;
    if (i < n4) {
        float4 v = ((const float4*)src)[i];
        ushort4 o;
        o.x = f2bf(v.x); o.y = f2bf(v.y); o.z = f2bf(v.z); o.w = f2bf(v.w);
        ((ushort4*)dst)[i] = o;
    }
}

// ---------------- GEMM: out_bf16 = A @ B^T + bias (M=4096,N=1024,K=1024) ----
__global__ __launch_bounds__(256) void gemm_q_kernel(
    const u16* __restrict__ A, const u16* __restrict__ Bw,
    const float* __restrict__ bias, u16* __restrict__ out) {
    const int K = 1024;
    __shared__ __align__(16) u16 Al[128 * 32];
    __shared__ __align__(16) u16 Bl[128 * 32];
    int t = threadIdx.x, w = t >> 6, l = t & 63;
    int wr = w >> 1, wc = w & 1;
    int row0 = blockIdx.y * 128, col0 = blockIdx.x * 128;
    int ar = t >> 2, ac = (t & 3) * 8;
    f32x4 acc[4][4] = {};
    for (int k0 = 0; k0 < K; k0 += 32) {
        __syncthreads();
        GLOAD_LDS16(A + (size_t)(row0 + ar) * K + k0 + ac, &Al[ar * 32 + ac]);
        GLOAD_LDS16(A + (size_t)(row0 + 64 + ar) * K + k0 + ac, &Al[(64 + ar) * 32 + ac]);
        GLOAD_LDS16(Bw + (size_t)(col0 + ar) * K + k0 + ac, &Bl[ar * 32 + ac]);
        GLOAD_LDS16(Bw + (size_t)(col0 + 64 + ar) * K + k0 + ac, &Bl[(64 + ar) * 32 + ac]);
        __syncthreads();
        bf16x8 a[4], b[4];
#pragma unroll
        for (int m = 0; m < 4; m++)
            a[m] = *(const bf16x8*)&Al[(wr * 64 + m * 16 + (l & 15)) * 32 + ((l >> 4) * 8)];
#pragma unroll
        for (int n = 0; n < 4; n++)
            b[n] = *(const bf16x8*)&Bl[(wc * 64 + n * 16 + (l & 15)) * 32 + ((l >> 4) * 8)];
#pragma unroll
        for (int m = 0; m < 4; m++)
#pragma unroll
            for (int n = 0; n < 4; n++)
                acc[m][n] = __builtin_amdgcn_mfma_f32_16x16x32_bf16(a[m], b[n], acc[m][n], 0, 0, 0);
    }
    int cr = (l >> 4) * 4, cc = l & 15;
#pragma unroll
    for (int m = 0; m < 4; m++)
#pragma unroll
        for (int n = 0; n < 4; n++) {
            int col = col0 + wc * 64 + n * 16 + cc;
            float bv = bias[col];
#pragma unroll
            for (int r = 0; r < 4; r++) {
                int row = row0 + wr * 64 + m * 16 + cr + r;
                out[(size_t)row * 1024 + col] = f2bf(acc[m][n][r] + bv);
            }
        }
}

// ---------------- GEMM: x_f32 = A @ B^T + bias + resid ----------------
__global__ __launch_bounds__(256) void gemm_o_kernel(
    const u16* __restrict__ A, const u16* __restrict__ Bw,
    const float* __restrict__ bias, const float* __restrict__ resid,
    float* __restrict__ out) {
    const int K = 1024;
    __shared__ __align__(16) u16 Al[128 * 32];
    __shared__ __align__(16) u16 Bl[128 * 32];
    int t = threadIdx.x, w = t >> 6, l = t & 63;
    int wr = w >> 1, wc = w & 1;
    int row0 = blockIdx.y * 128, col0 = blockIdx.x * 128;
    int ar = t >> 2, ac = (t & 3) * 8;
    f32x4 acc[4][4] = {};
    for (int k0 = 0; k0 < K; k0 += 32) {
        __syncthreads();
        GLOAD_LDS16(A + (size_t)(row0 + ar) * K + k0 + ac, &Al[ar * 32 + ac]);
        GLOAD_LDS16(A + (size_t)(row0 + 64 + ar) * K + k0 + ac, &Al[(64 + ar) * 32 + ac]);
        GLOAD_LDS16(Bw + (size_t)(col0 + ar) * K + k0 + ac, &Bl[ar * 32 + ac]);
        GLOAD_LDS16(Bw + (size_t)(col0 + 64 + ar) * K + k0 + ac, &Bl[(64 + ar) * 32 + ac]);
        __syncthreads();
        bf16x8 a[4], b[4];
#pragma unroll
        for (int m = 0; m < 4; m++)
            a[m] = *(const bf16x8*)&Al[(wr * 64 + m * 16 + (l & 15)) * 32 + ((l >> 4) * 8)];
#pragma unroll
        for (int n = 0; n < 4; n++)
            b[n] = *(const bf16x8*)&Bl[(wc * 64 + n * 16 + (l & 15)) * 32 + ((l >> 4) * 8)];
#pragma unroll
        for (int m = 0; m < 4; m++)
#pragma unroll
            for (int n = 0; n < 4; n++)
                acc[m][n] = __builtin_amdgcn_mfma_f32_16x16x32_bf16(a[m], b[n], acc[m][n], 0, 0, 0);
    }
    int cr = (l >> 4) * 4, cc = l & 15;
#pragma unroll
    for (int m = 0; m < 4; m++)
#pragma unroll
        for (int n = 0; n < 4; n++) {
            int col = col0 + wc * 64 + n * 16 + cc;
            float bv = bias[col];
#pragma unroll
            for (int r = 0; r < 4; r++) {
                int row = row0 + wr * 64 + m * 16 + cr + r;
                out[(size_t)row * 1024 + col] =
                    acc[m][n][r] + bv + resid[(size_t)row * 1024 + col];
            }
        }
}

// ---------------- per-head transpose: Qt[b,h,dh,s] = Q[b,s,h*64+dh] ----------
// FIXED: previous version only covered 32 of 64 rows/dims (t>>3 in [0,32)).
__global__ __launch_bounds__(256) void transpose_q(const u16* __restrict__ Q,
                                                   u16* __restrict__ Qt) {
    __shared__ u16 T[64][72];
    int t = threadIdx.x;
    int s0 = blockIdx.x * 64, h = blockIdx.y, b = blockIdx.z;
    int c8 = (t & 7) * 8;
#pragma unroll
    for (int half = 0; half < 2; half++) {
        int r = (t >> 3) + half * 32;
        us8 v = *(const us8*)(Q + (size_t)(b * 2048 + s0 + r) * 1024 + h * 64 + c8);
#pragma unroll
        for (int j = 0; j < 8; j++) T[r][c8 + j] = v[j];
    }
    __syncthreads();
    int s8 = (t & 7) * 8;
#pragma unroll
    for (int half = 0; half < 2; half++) {
        int d = (t >> 3) + half * 32;
        us8 o;
#pragma unroll
        for (int j = 0; j < 8; j++) o[j] = T[s8 + j][d];
        *(us8*)(Qt + (size_t)((b * 16 + h) * 64 + d) * 2048 + s0 + s8) = o;
    }
}

// ---------------- fused attention (2-pass online softmax) ----------------
__global__ __launch_bounds__(256) void attn_kernel(
    const u16* __restrict__ Q,   // [B,S,D] bf16
    const u16* __restrict__ Qt,  // [B,H,DH,S] bf16
    const float* __restrict__ mask, // [B,S]
    float* __restrict__ probs,   // [B,H,S,S] fp32
    u16* __restrict__ ctx) {     // [B,S,D] bf16
    const int S = 2048, D = 1024;
    __shared__ __align__(16) u16 Ql[64 * 64];
    __shared__ __align__(16) u16 Kl[64 * 64];
    __shared__ __align__(16) u16 Vl[64 * 64]; // V^T tile [d][k]
    __shared__ __align__(16) u16 Pl[4][16 * 64];
    int t = threadIdx.x, w = t >> 6, l = t & 63;
    int qt = blockIdx.x, h = blockIdx.y, b = blockIdx.z;
    int lr = t >> 3, lc = (t & 7) * 8;

    GLOAD_LDS16(Q + ((size_t)b * S + qt * 64 + lr) * D + h * 64 + lc, &Ql[lr * 64 + lc]);
    GLOAD_LDS16(Q + ((size_t)b * S + qt * 64 + 32 + lr) * D + h * 64 + lc, &Ql[(32 + lr) * 64 + lc]);
    __syncthreads();
    bf16x8 aq[2];
#pragma unroll
    for (int ks = 0; ks < 2; ks++)
        aq[ks] = *(const bf16x8*)&Ql[(w * 16 + (l & 15)) * 64 + ks * 32 + (l >> 4) * 8];

    int cr = (l >> 4) * 4, cc = l & 15;
    int qrow[4];
    float m_run[4], l_run[4];
#pragma unroll
    for (int r = 0; r < 4; r++) {
        qrow[r] = qt * 64 + w * 16 + cr + r;
        m_run[r] = -__builtin_inff();
        l_run[r] = 0.f;
    }

    // ---- pass 1: online (m, l) ----
    for (int kt = 0; kt <= qt; kt++) {
        __syncthreads();
        GLOAD_LDS16(Q + ((size_t)b * S + kt * 64 + lr) * D + h * 64 + lc, &Kl[lr * 64 + lc]);
        GLOAD_LDS16(Q + ((size_t)b * S + kt * 64 + 32 + lr) * D + h * 64 + lc, &Kl[(32 + lr) * 64 + lc]);
        __syncthreads();
        float sv[4][4];
#pragma unroll
        for (int n = 0; n < 4; n++) {
            f32x4 sacc = {};
            bf16x8 b0 = *(const bf16x8*)&Kl[(n * 16 + (l & 15)) * 64 + (l >> 4) * 8];
            bf16x8 b1 = *(const bf16x8*)&Kl[(n * 16 + (l & 15)) * 64 + 32 + (l >> 4) * 8];
            sacc = __builtin_amdgcn_mfma_f32_16x16x32_bf16(aq[0], b0, sacc, 0, 0, 0);
            sacc = __builtin_amdgcn_mfma_f32_16x16x32_bf16(aq[1], b1, sacc, 0, 0, 0);
            int kg = kt * 64 + n * 16 + cc;
            float padd = (1.0f - mask[b * S + kg]) * NEGV;
#pragma unroll
            for (int r = 0; r < 4; r++) {
                float s = sacc[r] * 0.03125f + padd;
                if (kg > qrow[r]) s = NEGV;
                sv[n][r] = s;
            }
        }
#pragma unroll
        for (int r = 0; r < 4; r++) {
            float tm = fmaxf(fmaxf(sv[0][r], sv[1][r]), fmaxf(sv[2][r], sv[3][r]));
#pragma unroll
            for (int mk = 1; mk < 16; mk <<= 1) tm = fmaxf(tm, __shfl_xor(tm, mk));
            float mn = fmaxf(m_run[r], tm);
            float se = __expf(sv[0][r] - mn) + __expf(sv[1][r] - mn) +
                       __expf(sv[2][r] - mn) + __expf(sv[3][r] - mn);
#pragma unroll
            for (int mk = 1; mk < 16; mk <<= 1) se += __shfl_xor(se, mk);
            l_run[r] = l_run[r] * __expf(m_run[r] - mn) + se;
            m_run[r] = mn;
        }
    }
    float rl[4];
#pragma unroll
    for (int r = 0; r < 4; r++) rl[r] = 1.0f / l_run[r];

    f32x4 cacc[4] = {};
    size_t pb = ((size_t)(b * 16 + h)) * S * S;

    // ---- pass 2: probs write + PV ----
    for (int kt = 0; kt <= qt; kt++) {
        __syncthreads();
        GLOAD_LDS16(Q + ((size_t)b * S + kt * 64 + lr) * D + h * 64 + lc, &Kl[lr * 64 + lc]);
        GLOAD_LDS16(Q + ((size_t)b * S + kt * 64 + 32 + lr) * D + h * 64 + lc, &Kl[(32 + lr) * 64 + lc]);
        GLOAD_LDS16(Qt + ((size_t)((b * 16 + h) * 64) + lr) * S + kt * 64 + lc, &Vl[lr * 64 + lc]);
        GLOAD_LDS16(Qt + ((size_t)((b * 16 + h) * 64) + 32 + lr) * S + kt * 64 + lc, &Vl[(32 + lr) * 64 + lc]);
        __syncthreads();
#pragma unroll
        for (int n = 0; n < 4; n++) {
            f32x4 sacc = {};
            bf16x8 b0 = *(const bf16x8*)&Kl[(n * 16 + (l & 15)) * 64 + (l >> 4) * 8];
            bf16x8 b1 = *(const bf16x8*)&Kl[(n * 16 + (l & 15)) * 64 + 32 + (l >> 4) * 8];
            sacc = __builtin_amdgcn_mfma_f32_16x16x32_bf16(aq[0], b0, sacc, 0, 0, 0);
            sacc = __builtin_amdgcn_mfma_f32_16x16x32_bf16(aq[1], b1, sacc, 0, 0, 0);
            int kg = kt * 64 + n * 16 + cc;
            float padd = (1.0f - mask[b * S + kg]) * NEGV;
#pragma unroll
            for (int r = 0; r < 4; r++) {
                float s = sacc[r] * 0.03125f + padd;
                if (kg > qrow[r]) s = NEGV;
                float p = __expf(s - m_run[r]) * rl[r];
                probs[pb + (size_t)qrow[r] * S + kg] = p;
                Pl[w][(cr + r) * 64 + n * 16 + cc] = f2bf(p);
            }
        }
        __syncthreads();
        bf16x8 pa[2];
#pragma unroll
        for (int ks = 0; ks < 2; ks++)
            pa[ks] = *(const bf16x8*)&Pl[w][(l & 15) * 64 + ks * 32 + (l >> 4) * 8];
#pragma unroll
        for (int n = 0; n < 4; n++) {
            bf16x8 v0 = *(const bf16x8*)&Vl[(n * 16 + (l & 15)) * 64 + (l >> 4) * 8];
            bf16x8 v1 = *(const bf16x8*)&Vl[(n * 16 + (l & 15)) * 64 + 32 + (l >> 4) * 8];
            cacc[n] = __builtin_amdgcn_mfma_f32_16x16x32_bf16(pa[0], v0, cacc[n], 0, 0, 0);
            cacc[n] = __builtin_amdgcn_mfma_f32_16x16x32_bf16(pa[1], v1, cacc[n], 0, 0, 0);
        }
    }

    // ---- zero-fill future-k tiles (exp underflows to exactly 0 in ref) ----
    for (int kt = qt + 1; kt < 32; kt++) {
        float4 z = {0.f, 0.f, 0.f, 0.f};
#pragma unroll
        for (int j = 0; j < 4; j++) {
            int slot = t + j * 256;
            int rr = slot >> 4, c4 = (slot & 15) * 4;
            *(float4*)&probs[pb + (size_t)(qt * 64 + rr) * S + kt * 64 + c4] = z;
        }
    }

    // ---- ctx store ----
#pragma unroll
    for (int n = 0; n < 4; n++)
#pragma unroll
        for (int r = 0; r < 4; r++)
            ctx[((size_t)b * S + qrow[r]) * D + h * 64 + n * 16 + cc] = f2bf(cacc[n][r]);
}

// ---------------- LayerNorm (block per row) ----------------
__global__ __launch_bounds__(256) void ln_kernel(const float* __restrict__ x,
                                                 const float* __restrict__ gamma,
                                                 const float* __restrict__ beta,
                                                 float* __restrict__ out) {
    int row = blockIdx.x, t = threadIdx.x, w = t >> 6, l = t & 63;
    __shared__ float red[8];
    float4 v = ((const float4*)(x + (size_t)row * 1024))[t];
    float s1 = v.x + v.y + v.z + v.w;
    float s2 = v.x * v.x + v.y * v.y + v.z * v.z + v.w * v.w;
#pragma unroll
    for (int mk = 1; mk < 64; mk <<= 1) {
        s1 += __shfl_xor(s1, mk);
        s2 += __shfl_xor(s2, mk);
    }
    if (l == 0) { red[w] = s1; red[4 + w] = s2; }
    __syncthreads();
    float S1 = red[0] + red[1] + red[2] + red[3];
    float S2 = red[4] + red[5] + red[6] + red[7];
    float mu = S1 * (1.0f / 1024.0f);
    float var = S2 * (1.0f / 1024.0f) - mu * mu;
    float inv = rsqrtf(var + 1e-12f);
    float4 g = ((const float4*)gamma)[t];
    float4 bt = ((const float4*)beta)[t];
    float4 o;
    o.x = g.x * (v.x - mu) * inv + bt.x;
    o.y = g.y * (v.y - mu) * inv + bt.y;
    o.z = g.z * (v.z - mu) * inv + bt.z;
    o.w = g.w * (v.w - mu) * inv + bt.w;
    ((float4*)(out + (size_t)row * 1024))[t] = o;
}

extern "C" void kernel_launch(void* const* d_in, const int* in_sizes, int n_in,
                              void* d_out, int out_size, void* d_ws, size_t ws_size,
                              hipStream_t stream) {
    const float* emb   = (const float*)d_in[0];
    const float* mask  = (const float*)d_in[1];
    const float* Wq    = (const float*)d_in[2];
    const float* bq    = (const float*)d_in[3];
    const float* Wo    = (const float*)d_in[8];
    const float* bo    = (const float*)d_in[9];
    const float* gamma = (const float*)d_in[10];
    const float* beta  = (const float*)d_in[11];
    float* out_ln = (float*)d_out;
    float* probs  = (float*)d_out + (size_t)2 * 2048 * 1024;

    char* ws = (char*)d_ws;
    u16* emb_bf = (u16*)ws; ws += (size_t)8388608;
    u16* Wq_bf  = (u16*)ws; ws += (size_t)2097152;
    u16* Wo_bf  = (u16*)ws; ws += (size_t)2097152;
    u16* Qb     = (u16*)ws; ws += (size_t)8388608;
    u16* Qtb    = (u16*)ws; ws += (size_t)8388608;
    u16* ctxb   = (u16*)ws; ws += (size_t)8388608;
    float* xf   = (float*)ws;

    cvt_bf16<<<4096, 256, 0, stream>>>(emb, emb_bf, 1048576);
    cvt_bf16<<<1024, 256, 0, stream>>>(Wq, Wq_bf, 262144);
    cvt_bf16<<<1024, 256, 0, stream>>>(Wo, Wo_bf, 262144);
    gemm_q_kernel<<<dim3(8, 32), 256, 0, stream>>>(emb_bf, Wq_bf, bq, Qb);
    transpose_q<<<dim3(32, 16, 2), 256, 0, stream>>>(Qb, Qtb);
    attn_kernel<<<dim3(32, 16, 2), 256, 0, stream>>>(Qb, Qtb, mask, probs, ctxb);
    gemm_o_kernel<<<dim3(8, 32), 256, 0, stream>>>(ctxb, Wo_bf, bo, emb, xf);
    ln_kernel<<<4096, 256, 0, stream>>>(xf, gamma, beta, out_ln);
}